// Round 9
// baseline (211.903 us; speedup 1.0000x reference)
//
#include <hip/hip_runtime.h>

#define BB 16
#define LL 200
#define HID 128
#define NH 4
#define DH 32
#define IH 96
#define NROW (BB*LL)          // 3200
#define NT 257                // distinct time-interval values
#define QTKS (NH*NT)          // 1028
#define LNEPS 1e-8f

// ---------------- embed: seqs = embed(log_seqs) * sqrt(96), zeroed where id==0
__global__ void k_embed(const int* __restrict__ logs,
                        const int* __restrict__ meta,
                        const float* __restrict__ iW,
                        const float* __restrict__ bW,
                        const float* __restrict__ cW,
                        float* __restrict__ seqs)
{
    int row = blockIdx.x;
    int d = threadIdx.x;
    int id = logs[row];
    float v;
    if (d < IH)            v = iW[(size_t)id*IH + d];
    else if (d < IH + 16)  v = bW[meta[2*id]   *16 + (d-IH)];
    else                   v = cW[meta[2*id+1] *16 + (d-IH-16)];
    v *= 9.797958971132712f;   // sqrt(96)
    if (id == 0) v = 0.f;
    seqs[(size_t)row*HID + d] = v;
}

// ---------------- fused attn-LN + Q/K/V GEMVs, 8 rows/block
__global__ __launch_bounds__(512) void k_lnqkv(
    const float* __restrict__ seqs,
    const float* __restrict__ lns, const float* __restrict__ lnb,
    const float* __restrict__ Qw, const float* __restrict__ Qb,
    const float* __restrict__ Kw, const float* __restrict__ Kb,
    const float* __restrict__ Vw, const float* __restrict__ Vb,
    const float* __restrict__ posK, const float* __restrict__ posV,
    float* __restrict__ Qn, float* __restrict__ qbuf,
    float* __restrict__ kbuf, float* __restrict__ vbuf)
{
    __shared__ float xs[8][HID];
    __shared__ float qn[8][HID];
    __shared__ float red[4][HID];
    int tid = threadIdx.x;
    int g = tid >> 7, col = tid & 127;
    int r0 = blockIdx.x * 8;

    #pragma unroll
    for (int p = 0; p < 2; ++p) {
        int rr = g + p*4;
        int row = r0 + rr;
        float x = seqs[(size_t)row*HID + col];
        xs[rr][col] = x;
        red[g][col] = x;
        __syncthreads();
        for (int off = 64; off; off >>= 1) { if (col < off) red[g][col] += red[g][col+off]; __syncthreads(); }
        float mu = red[g][0] * (1.f/HID);
        __syncthreads();
        float c = x - mu;
        red[g][col] = c*c; __syncthreads();
        for (int off = 64; off; off >>= 1) { if (col < off) red[g][col] += red[g][col+off]; __syncthreads(); }
        float ln = c * rsqrtf(red[g][0]*(1.f/HID) + LNEPS) * lns[col] + lnb[col];
        qn[rr][col] = ln;
        Qn[(size_t)row*HID + col] = ln;
        __syncthreads();
    }

    int rA = 2*g, rB = 2*g + 1;
    float aq0 = Qb[col], aq1 = aq0;
    float ak0 = Kb[col], ak1 = ak0;
    float av0 = Vb[col], av1 = av0;
    const float* q0 = qn[rA]; const float* q1 = qn[rB];
    const float* x0 = xs[rA]; const float* x1 = xs[rB];
    #pragma unroll 4
    for (int kk = 0; kk < HID; ++kk) {
        float wq = Qw[kk*HID + col];
        float wk = Kw[kk*HID + col];
        float wv = Vw[kk*HID + col];
        aq0 += q0[kk]*wq; aq1 += q1[kk]*wq;
        ak0 += x0[kk]*wk; ak1 += x1[kk]*wk;
        av0 += x0[kk]*wv; av1 += x1[kk]*wv;
    }
    int rowA = r0 + rA, rowB = r0 + rB;
    int lA = rowA % LL, lB = rowB % LL;
    qbuf[(size_t)rowA*HID + col] = aq0;
    qbuf[(size_t)rowB*HID + col] = aq1;
    kbuf[(size_t)rowA*HID + col] = ak0 + posK[lA*HID + col];
    kbuf[(size_t)rowB*HID + col] = ak1 + posK[lB*HID + col];
    vbuf[(size_t)rowA*HID + col] = av0 + posV[lA*HID + col];
    vbuf[(size_t)rowB*HID + col] = av1 + posV[lB*HID + col];
}

// ---------------- QTK[row][h][t] = q[row][h] . tK[t][h]  (8 rows/block)
__global__ __launch_bounds__(256) void k_qtk(
    const float* __restrict__ qbuf,
    const float* __restrict__ tK,
    float* __restrict__ QTK)
{
    __shared__ float qs[8][HID];
    int tid = threadIdx.x;
    int r0 = blockIdx.x * 8;
    for (int e = tid; e < 8*HID; e += 256)
        qs[e >> 7][e & 127] = qbuf[(size_t)(r0 + (e >> 7))*HID + (e & 127)];
    __syncthreads();

    for (int p = tid; p < QTKS; p += 256) {
        int h = p / NT;
        int t = p - h*NT;
        const float4* tr = (const float4*)(tK + (size_t)t*HID + h*DH);
        float4 tk[8];
        #pragma unroll
        for (int r = 0; r < 8; ++r) tk[r] = tr[r];
        #pragma unroll
        for (int r = 0; r < 8; ++r) {
            const float* qp = qs[r] + h*DH;
            float acc = 0.f;
            #pragma unroll
            for (int u = 0; u < 8; ++u) {
                float4 k4 = tk[u];
                acc += qp[4*u+0]*k4.x + qp[4*u+1]*k4.y + qp[4*u+2]*k4.z + qp[4*u+3]*k4.w;
            }
            QTK[(size_t)(r0 + r)*QTKS + p] = acc;
        }
    }
}

// ---------------- attention: block=(h,i), 16 waves = 16 batches
// score: q.kp stream + QTK[t] 4B gather (L1); PV: vp stream + tV head-slice in LDS
__global__ __launch_bounds__(1024) void k_attn(
    const float*  __restrict__ q,    // qbuf  [NROW][128]
    const float4* __restrict__ kp4,  // k + posK, [NROW][32]
    const float4* __restrict__ vp4,  // v + posV
    const float4* __restrict__ Qn4,
    const float*  __restrict__ QTK,  // [NROW][4][257]
    const float4* __restrict__ tV4,  // [257][32]
    const int* __restrict__ tmat, const int* __restrict__ logs,
    float4* __restrict__ out4)
{
    __shared__ float4 tv_lds[256*8];   // 32 KiB, XOR-swizzled; t==256 -> global

    int bid = blockIdx.x;
    int h   = bid & 3;
    int i   = 199 - (bid >> 2);       // biggest rows dispatched first
    int tid = threadIdx.x;

    for (int e = tid; e < 2048; e += 1024) {
        int t = e >> 3, s = e & 7;
        tv_lds[t*8 + (s ^ (t & 7))] = tV4[(size_t)t*32 + h*8 + s];
    }
    __syncthreads();

    int b = __builtin_amdgcn_readfirstlane(tid >> 6);   // wave id = batch
    int lane = tid & 63;
    int row = b*LL + i;
    int valid = (logs[row] != 0);
    int nj = valid ? (i + 1) : LL;

    // q slice: wave-uniform address -> scalar loads (stays in SGPRs)
    const float* qp = q + (size_t)row*HID + h*DH;
    float qv[32];
    #pragma unroll
    for (int t = 0; t < 32; ++t) qv[t] = qp[t];

    const float* qtkg = QTK + (size_t)row*QTKS + h*NT;  // wave-uniform base

    // time indices
    int tsv[4];
    #pragma unroll
    for (int c = 0; c < 4; ++c) {
        int j = c*64 + lane;
        tsv[c] = (j < nj) ? tmat[(size_t)row*LL + j] : 0;
    }

    // scores: s = (q.k_j + QTK[t_ij]) / sqrt(32)
    float ev[4];
    #pragma unroll
    for (int c = 0; c < 4; ++c) {
        int j = c*64 + lane;
        float s = -INFINITY;
        if (j < nj) {
            if (valid) {
                float qtk = qtkg[tsv[c]];
                const float4* kr = kp4 + ((size_t)(b*LL + j))*32 + h*8;
                float acc = 0.f;
                #pragma unroll
                for (int r = 0; r < 8; ++r) {
                    float4 kx = kr[r];
                    acc += qv[4*r+0]*kx.x + qv[4*r+1]*kx.y
                         + qv[4*r+2]*kx.z + qv[4*r+3]*kx.w;
                }
                s = (acc + qtk) * 0.17677669529663687f; // 1/sqrt(32)
            } else {
                s = 0.f;                                 // invalid row -> uniform softmax
            }
        }
        ev[c] = s;
    }

    // softmax (in-register, wave-level)
    float m = fmaxf(fmaxf(ev[0], ev[1]), fmaxf(ev[2], ev[3]));
    #pragma unroll
    for (int off = 32; off; off >>= 1) m = fmaxf(m, __shfl_xor(m, off));
    float ssum = 0.f;
    #pragma unroll
    for (int c = 0; c < 4; ++c) {
        int j = c*64 + lane;
        float e = (j < nj) ? __expf(ev[c] - m) : 0.f;
        ev[c] = e; ssum += e;
    }
    #pragma unroll
    for (int off = 32; off; off >>= 1) ssum += __shfl_xor(ssum, off);
    float inv = 1.f / ssum;

    // PV: lanes = (jc in 0..7) x (d4 in 0..7)
    int jc = lane >> 3, d4 = lane & 7;
    float4 acc = {0.f, 0.f, 0.f, 0.f};
    #pragma unroll
    for (int c = 0; c < 4; ++c) {
        int jlo = c*64;
        int jhi = (jlo + 64 < nj) ? (jlo + 64) : nj;
        for (int jj = jlo; jj < jhi; jj += 8) {
            int j = jj + jc;
            float a  = __shfl(ev[c],  j & 63);
            int  tsj = __shfl(tsv[c], j & 63);
            if (j < jhi) {
                float4 vx = vp4[((size_t)(b*LL + j))*32 + h*8 + d4];
                float4 tx;
                if (tsj < 256) tx = tv_lds[tsj*8 + (d4 ^ (tsj & 7))];
                else           tx = tV4[(size_t)256*32 + h*8 + d4];
                acc.x += a*(vx.x+tx.x); acc.y += a*(vx.y+tx.y);
                acc.z += a*(vx.z+tx.z); acc.w += a*(vx.w+tx.w);
            }
        }
    }
    #pragma unroll
    for (int off = 8; off < 64; off <<= 1) {
        acc.x += __shfl_xor(acc.x, off);
        acc.y += __shfl_xor(acc.y, off);
        acc.z += __shfl_xor(acc.z, off);
        acc.w += __shfl_xor(acc.w, off);
    }
    if (jc == 0) {
        float4 qn = Qn4[(size_t)row*32 + h*8 + d4];
        float4 o;
        o.x = qn.x + acc.x*inv;
        o.y = qn.y + acc.y*inv;
        o.z = qn.z + acc.z*inv;
        o.w = qn.w + acc.w*inv;
        out4[(size_t)row*32 + h*8 + d4] = o;
    }
}

// ---------------- fused fwd-LN + FFN + residual + valid mask, 8 rows/block
__global__ __launch_bounds__(512) void k_ffn(
    const float* __restrict__ seqs_in,
    const float* __restrict__ lns, const float* __restrict__ lnb,
    const float* __restrict__ c1w, const float* __restrict__ c1b,
    const float* __restrict__ c2w, const float* __restrict__ c2b,
    const int* __restrict__ logs,
    float* __restrict__ seqs_out)
{
    __shared__ float xs[8][HID];
    __shared__ float h1[8][HID];
    __shared__ float red[4][HID];
    int tid = threadIdx.x;
    int g = tid >> 7, col = tid & 127;
    int r0 = blockIdx.x * 8;

    #pragma unroll
    for (int p = 0; p < 2; ++p) {
        int rr = g + p*4;
        int row = r0 + rr;
        float x = seqs_in[(size_t)row*HID + col];
        red[g][col] = x;
        __syncthreads();
        for (int off = 64; off; off >>= 1) { if (col < off) red[g][col] += red[g][col+off]; __syncthreads(); }
        float mu = red[g][0] * (1.f/HID);
        __syncthreads();
        float c = x - mu;
        red[g][col] = c*c; __syncthreads();
        for (int off = 64; off; off >>= 1) { if (col < off) red[g][col] += red[g][col+off]; __syncthreads(); }
        xs[rr][col] = c * rsqrtf(red[g][0]*(1.f/HID) + LNEPS) * lns[col] + lnb[col];
        __syncthreads();
    }

    int rA = 2*g, rB = 2*g + 1;
    {
        float a0 = c1b[col], a1 = a0;
        const float* x0 = xs[rA]; const float* x1 = xs[rB];
        #pragma unroll 4
        for (int kk = 0; kk < HID; ++kk) {
            float w = c1w[kk*HID + col];
            a0 += x0[kk]*w; a1 += x1[kk]*w;
        }
        h1[rA][col] = fmaxf(a0, 0.f);
        h1[rB][col] = fmaxf(a1, 0.f);
    }
    __syncthreads();

    {
        float a0 = c2b[col], a1 = a0;
        const float* y0 = h1[rA]; const float* y1 = h1[rB];
        #pragma unroll 4
        for (int kk = 0; kk < HID; ++kk) {
            float w = c2w[kk*HID + col];
            a0 += y0[kk]*w; a1 += y1[kk]*w;
        }
        int rowA = r0 + rA, rowB = r0 + rB;
        float o0 = xs[rA][col] + a0;
        float o1 = xs[rB][col] + a1;
        if (logs[rowA] == 0) o0 = 0.f;
        if (logs[rowB] == 0) o1 = 0.f;
        seqs_out[(size_t)rowA*HID + col] = o0;
        seqs_out[(size_t)rowB*HID + col] = o1;
    }
}

// ---------------- last LN + pos/neg logits
__global__ void k_logits(const float* __restrict__ seqs,
                         const float* __restrict__ ls, const float* __restrict__ lb,
                         const int* __restrict__ pos, const int* __restrict__ neg,
                         const int* __restrict__ meta,
                         const float* __restrict__ iW, const float* __restrict__ bW,
                         const float* __restrict__ cW,
                         float* __restrict__ out)
{
    __shared__ float sh[HID];
    int row = blockIdx.x, d = threadIdx.x;
    float x = seqs[(size_t)row*HID + d];
    sh[d] = x; __syncthreads();
    for (int off = 64; off; off >>= 1) { if (d < off) sh[d] += sh[d+off]; __syncthreads(); }
    float mu = sh[0] * (1.f/HID);
    __syncthreads();
    float c = x - mu;
    sh[d] = c*c; __syncthreads();
    for (int off = 64; off; off >>= 1) { if (d < off) sh[d] += sh[d+off]; __syncthreads(); }
    float f = c * rsqrtf(sh[0]*(1.f/HID) + LNEPS) * ls[d] + lb[d];
    __syncthreads();

    int pid = pos[row];
    float e;
    if (d < IH)           e = iW[(size_t)pid*IH + d];
    else if (d < IH + 16) e = bW[meta[2*pid]   *16 + (d-IH)];
    else                  e = cW[meta[2*pid+1] *16 + (d-IH-16)];
    sh[d] = f * e; __syncthreads();
    for (int off = 64; off; off >>= 1) { if (d < off) sh[d] += sh[d+off]; __syncthreads(); }
    if (d == 0) out[row] = sh[0];
    __syncthreads();

    int nid = neg[row];
    if (d < IH)           e = iW[(size_t)nid*IH + d];
    else if (d < IH + 16) e = bW[meta[2*nid]   *16 + (d-IH)];
    else                  e = cW[meta[2*nid+1] *16 + (d-IH-16)];
    sh[d] = f * e; __syncthreads();
    for (int off = 64; off; off >>= 1) { if (d < off) sh[d] += sh[d+off]; __syncthreads(); }
    if (d == 0) out[NROW + row] = sh[0];
}

extern "C" void kernel_launch(void* const* d_in, const int* in_sizes, int n_in,
                              void* d_out, int out_size, void* d_ws, size_t ws_size,
                              hipStream_t stream)
{
    const int*  logs = (const int*)d_in[1];
    const int*  tmat = (const int*)d_in[2];
    const int*  pos  = (const int*)d_in[3];
    const int*  neg  = (const int*)d_in[4];
    const int*  meta = (const int*)d_in[5];
    const float* iW   = (const float*)d_in[6];
    const float* bW   = (const float*)d_in[7];
    const float* cW   = (const float*)d_in[8];
    const float* posK = (const float*)d_in[9];
    const float* posV = (const float*)d_in[10];
    const float* tK   = (const float*)d_in[11];
    const float* tV   = (const float*)d_in[12];
    const float* attn_s = (const float*)d_in[13];
    const float* attn_b = (const float*)d_in[14];
    const float* Qw = (const float*)d_in[15];
    const float* Qb = (const float*)d_in[16];
    const float* Kw = (const float*)d_in[17];
    const float* Kb = (const float*)d_in[18];
    const float* Vw = (const float*)d_in[19];
    const float* Vb = (const float*)d_in[20];
    const float* fwd_s = (const float*)d_in[21];
    const float* fwd_b = (const float*)d_in[22];
    const float* c1w = (const float*)d_in[23];
    const float* c1b = (const float*)d_in[24];
    const float* c2w = (const float*)d_in[25];
    const float* c2b = (const float*)d_in[26];
    const float* lls = (const float*)d_in[27];
    const float* llb = (const float*)d_in[28];

    const size_t RC = (size_t)NROW * HID;
    float* seqs = (float*)d_ws;
    float* Qn   = seqs + RC;
    float* qbuf = Qn   + RC;
    float* kbuf = qbuf + RC;
    float* vbuf = kbuf + RC;
    float* QTK  = vbuf + RC;   // [NROW][1028] = 13.2 MB

    k_embed<<<NROW, 128, 0, stream>>>(logs, meta, iW, bW, cW, seqs);

    for (int i = 0; i < 2; ++i) {
        size_t wo = (size_t)i * HID * HID;
        size_t bo = (size_t)i * HID;
        k_lnqkv<<<NROW/8, 512, 0, stream>>>(seqs, attn_s + bo, attn_b + bo,
                                            Qw + wo, Qb + bo, Kw + wo, Kb + bo,
                                            Vw + wo, Vb + bo, posK, posV,
                                            Qn, qbuf, kbuf, vbuf);
        k_qtk<<<NROW/8, 256, 0, stream>>>(qbuf, tK, QTK);
        k_attn<<<NH*LL, 1024, 0, stream>>>(qbuf, (const float4*)kbuf,
                                           (const float4*)vbuf, (const float4*)Qn,
                                           QTK, (const float4*)tV,
                                           tmat, logs, (float4*)seqs);
        k_ffn<<<NROW/8, 512, 0, stream>>>(seqs, fwd_s + bo, fwd_b + bo,
                                          c1w + wo, c1b + bo, c2w + wo, c2b + bo,
                                          logs, seqs);
    }

    k_logits<<<NROW, 128, 0, stream>>>(seqs, lls, llb, pos, neg, meta, iW, bW, cW, (float*)d_out);
}

// Round 10
// 179.171 us; speedup vs baseline: 1.1827x; 1.1827x over previous
//
#include <hip/hip_runtime.h>

#define BB 16
#define LL 200
#define HID 128
#define NH 4
#define DH 32
#define IH 96
#define NROW (BB*LL)          // 3200
#define LNEPS 1e-8f

__device__ __forceinline__ float embed_val(int id, int col,
                                           const int* __restrict__ meta,
                                           const float* __restrict__ iW,
                                           const float* __restrict__ bW,
                                           const float* __restrict__ cW)
{
    float v;
    if (col < IH)           v = iW[(size_t)id*IH + col];
    else if (col < IH + 16) v = bW[meta[2*id]   *16 + (col-IH)];
    else                    v = cW[meta[2*id+1] *16 + (col-IH-16)];
    return v;
}

// ---------------- K1: embed + attn-LN + Q/K/V GEMVs, 8 rows/block
__global__ __launch_bounds__(512) void k_emb_lnqkv(
    const int* __restrict__ logs, const int* __restrict__ meta,
    const float* __restrict__ iW, const float* __restrict__ bW,
    const float* __restrict__ cW,
    const float* __restrict__ lns, const float* __restrict__ lnb,
    const float* __restrict__ Qw, const float* __restrict__ Qb,
    const float* __restrict__ Kw, const float* __restrict__ Kb,
    const float* __restrict__ Vw, const float* __restrict__ Vb,
    const float* __restrict__ posK, const float* __restrict__ posV,
    float* __restrict__ Qn, float* __restrict__ qbuf,
    float* __restrict__ kbuf, float* __restrict__ vbuf)
{
    __shared__ float xs[8][HID];
    __shared__ float qn[8][HID];
    __shared__ float red[4][HID];
    int tid = threadIdx.x;
    int g = tid >> 7, col = tid & 127;
    int r0 = blockIdx.x * 8;

    #pragma unroll
    for (int p = 0; p < 2; ++p) {
        int rr = g + p*4;
        int row = r0 + rr;
        int id = logs[row];
        float x = (id == 0) ? 0.f : embed_val(id, col, meta, iW, bW, cW) * 9.797958971132712f;
        xs[rr][col] = x;
        red[g][col] = x;
        __syncthreads();
        for (int off = 64; off; off >>= 1) { if (col < off) red[g][col] += red[g][col+off]; __syncthreads(); }
        float mu = red[g][0] * (1.f/HID);
        __syncthreads();
        float c = x - mu;
        red[g][col] = c*c; __syncthreads();
        for (int off = 64; off; off >>= 1) { if (col < off) red[g][col] += red[g][col+off]; __syncthreads(); }
        float ln = c * rsqrtf(red[g][0]*(1.f/HID) + LNEPS) * lns[col] + lnb[col];
        qn[rr][col] = ln;
        Qn[(size_t)row*HID + col] = ln;
        __syncthreads();
    }

    int rA = 2*g, rB = 2*g + 1;
    float aq0 = Qb[col], aq1 = aq0;
    float ak0 = Kb[col], ak1 = ak0;
    float av0 = Vb[col], av1 = av0;
    const float* q0 = qn[rA]; const float* q1 = qn[rB];
    const float* x0 = xs[rA]; const float* x1 = xs[rB];
    #pragma unroll 4
    for (int kk = 0; kk < HID; ++kk) {
        float wq = Qw[kk*HID + col];
        float wk = Kw[kk*HID + col];
        float wv = Vw[kk*HID + col];
        aq0 += q0[kk]*wq; aq1 += q1[kk]*wq;
        ak0 += x0[kk]*wk; ak1 += x1[kk]*wk;
        av0 += x0[kk]*wv; av1 += x1[kk]*wv;
    }
    int rowA = r0 + rA, rowB = r0 + rB;
    int lA = rowA % LL, lB = rowB % LL;
    qbuf[(size_t)rowA*HID + col] = aq0;
    qbuf[(size_t)rowB*HID + col] = aq1;
    kbuf[(size_t)rowA*HID + col] = ak0 + posK[lA*HID + col];
    kbuf[(size_t)rowB*HID + col] = ak1 + posK[lB*HID + col];
    vbuf[(size_t)rowA*HID + col] = av0 + posV[lA*HID + col];
    vbuf[(size_t)rowB*HID + col] = av1 + posV[lB*HID + col];
}

// ---------------- attention (unchanged from R8): block=(h,i), 16 waves = 16 batches
__global__ __launch_bounds__(1024) void k_attn(
    const float*  __restrict__ q,
    const float4* __restrict__ kp4,
    const float4* __restrict__ vp4,
    const float4* __restrict__ Qn4,
    const float4* __restrict__ tK4,
    const float4* __restrict__ tV4,
    const int* __restrict__ tmat, const int* __restrict__ logs,
    float4* __restrict__ out4)
{
    __shared__ float4 tk_lds[256*8];   // 32 KiB
    __shared__ float4 tv_lds[256*8];   // 32 KiB

    int bid = blockIdx.x;
    int h   = bid & 3;
    int i   = 199 - (bid >> 2);
    int tid = threadIdx.x;

    for (int e = tid; e < 2048; e += 1024) {
        int t = e >> 3, s = e & 7;
        int slot = s ^ (t & 7);
        tk_lds[t*8 + slot] = tK4[(size_t)t*32 + h*8 + s];
        tv_lds[t*8 + slot] = tV4[(size_t)t*32 + h*8 + s];
    }
    __syncthreads();

    int b = __builtin_amdgcn_readfirstlane(tid >> 6);
    int lane = tid & 63;
    int row = b*LL + i;
    int valid = (logs[row] != 0);
    int nj = valid ? (i + 1) : LL;

    const float* qp = q + (size_t)row*HID + h*DH;
    float qv[32];
    #pragma unroll
    for (int t = 0; t < 32; ++t) qv[t] = qp[t];

    int tsv[4];
    #pragma unroll
    for (int c = 0; c < 4; ++c) {
        int j = c*64 + lane;
        tsv[c] = (j < nj) ? tmat[(size_t)row*LL + j] : 0;
    }

    float ev[4];
    #pragma unroll
    for (int c = 0; c < 4; ++c) {
        int j = c*64 + lane;
        float s = -INFINITY;
        if (j < nj) {
            if (valid) {
                int t = tsv[c];
                const float4* kr = kp4 + ((size_t)(b*LL + j))*32 + h*8;
                float acc = 0.f;
                if (t < 256) {
                    const float4* tb = tk_lds + t*8;
                    int x = t & 7;
                    #pragma unroll
                    for (int r = 0; r < 8; ++r) {
                        float4 kx = kr[r], tx = tb[r ^ x];
                        acc += qv[4*r+0]*(kx.x+tx.x) + qv[4*r+1]*(kx.y+tx.y)
                             + qv[4*r+2]*(kx.z+tx.z) + qv[4*r+3]*(kx.w+tx.w);
                    }
                } else {
                    const float4* tr = tK4 + (size_t)256*32 + h*8;
                    #pragma unroll
                    for (int r = 0; r < 8; ++r) {
                        float4 kx = kr[r], tx = tr[r];
                        acc += qv[4*r+0]*(kx.x+tx.x) + qv[4*r+1]*(kx.y+tx.y)
                             + qv[4*r+2]*(kx.z+tx.z) + qv[4*r+3]*(kx.w+tx.w);
                    }
                }
                s = acc * 0.17677669529663687f;
            } else {
                s = 0.f;
            }
        }
        ev[c] = s;
    }

    float m = fmaxf(fmaxf(ev[0], ev[1]), fmaxf(ev[2], ev[3]));
    #pragma unroll
    for (int off = 32; off; off >>= 1) m = fmaxf(m, __shfl_xor(m, off));
    float ssum = 0.f;
    #pragma unroll
    for (int c = 0; c < 4; ++c) {
        int j = c*64 + lane;
        float e = (j < nj) ? __expf(ev[c] - m) : 0.f;
        ev[c] = e; ssum += e;
    }
    #pragma unroll
    for (int off = 32; off; off >>= 1) ssum += __shfl_xor(ssum, off);
    float inv = 1.f / ssum;

    int jc = lane >> 3, d4 = lane & 7;
    float4 acc = {0.f, 0.f, 0.f, 0.f};
    #pragma unroll
    for (int c = 0; c < 4; ++c) {
        int jlo = c*64;
        int jhi = (jlo + 64 < nj) ? (jlo + 64) : nj;
        for (int jj = jlo; jj < jhi; jj += 8) {
            int j = jj + jc;
            float a  = __shfl(ev[c],  j & 63);
            int  tsj = __shfl(tsv[c], j & 63);
            if (j < jhi) {
                float4 vx = vp4[((size_t)(b*LL + j))*32 + h*8 + d4];
                float4 tx;
                if (tsj < 256) tx = tv_lds[tsj*8 + (d4 ^ (tsj & 7))];
                else           tx = tV4[(size_t)256*32 + h*8 + d4];
                acc.x += a*(vx.x+tx.x); acc.y += a*(vx.y+tx.y);
                acc.z += a*(vx.z+tx.z); acc.w += a*(vx.w+tx.w);
            }
        }
    }
    #pragma unroll
    for (int off = 8; off < 64; off <<= 1) {
        acc.x += __shfl_xor(acc.x, off);
        acc.y += __shfl_xor(acc.y, off);
        acc.z += __shfl_xor(acc.z, off);
        acc.w += __shfl_xor(acc.w, off);
    }
    if (jc == 0) {
        float4 qn = Qn4[(size_t)row*32 + h*8 + d4];
        float4 o;
        o.x = qn.x + acc.x*inv;
        o.y = qn.y + acc.y*inv;
        o.z = qn.z + acc.z*inv;
        o.w = qn.w + acc.w*inv;
        out4[(size_t)row*32 + h*8 + d4] = o;
    }
}

// ---------------- K2: FFN(layer l) + attn-LN(l+1) + Q/K/V GEMVs(l+1), 8 rows/block
__global__ __launch_bounds__(512) void k_ffn_lnqkv(
    const float* __restrict__ seqs_in,          // attn(l) output
    const float* __restrict__ flns, const float* __restrict__ flnb,
    const float* __restrict__ c1w, const float* __restrict__ c1b,
    const float* __restrict__ c2w, const float* __restrict__ c2b,
    const int* __restrict__ logs,
    const float* __restrict__ lns, const float* __restrict__ lnb, // layer l+1
    const float* __restrict__ Qw, const float* __restrict__ Qb,
    const float* __restrict__ Kw, const float* __restrict__ Kb,
    const float* __restrict__ Vw, const float* __restrict__ Vb,
    const float* __restrict__ posK, const float* __restrict__ posV,
    float* __restrict__ Qn, float* __restrict__ qbuf,
    float* __restrict__ kbuf, float* __restrict__ vbuf)
{
    __shared__ float xs[8][HID];
    __shared__ float h1[8][HID];
    __shared__ float red[4][HID];
    __shared__ float sx[8][HID];   // post-FFN seqs
    __shared__ float qn[8][HID];
    int tid = threadIdx.x;
    int g = tid >> 7, col = tid & 127;
    int r0 = blockIdx.x * 8;

    // ---- FFN phase (layer l) ----
    #pragma unroll
    for (int p = 0; p < 2; ++p) {
        int rr = g + p*4;
        int row = r0 + rr;
        float x = seqs_in[(size_t)row*HID + col];
        red[g][col] = x;
        __syncthreads();
        for (int off = 64; off; off >>= 1) { if (col < off) red[g][col] += red[g][col+off]; __syncthreads(); }
        float mu = red[g][0] * (1.f/HID);
        __syncthreads();
        float c = x - mu;
        red[g][col] = c*c; __syncthreads();
        for (int off = 64; off; off >>= 1) { if (col < off) red[g][col] += red[g][col+off]; __syncthreads(); }
        xs[rr][col] = c * rsqrtf(red[g][0]*(1.f/HID) + LNEPS) * flns[col] + flnb[col];
        __syncthreads();
    }

    int rA = 2*g, rB = 2*g + 1;
    {
        float a0 = c1b[col], a1 = a0;
        const float* x0 = xs[rA]; const float* x1 = xs[rB];
        #pragma unroll 4
        for (int kk = 0; kk < HID; ++kk) {
            float w = c1w[kk*HID + col];
            a0 += x0[kk]*w; a1 += x1[kk]*w;
        }
        h1[rA][col] = fmaxf(a0, 0.f);
        h1[rB][col] = fmaxf(a1, 0.f);
    }
    __syncthreads();
    {
        float a0 = c2b[col], a1 = a0;
        const float* y0 = h1[rA]; const float* y1 = h1[rB];
        #pragma unroll 4
        for (int kk = 0; kk < HID; ++kk) {
            float w = c2w[kk*HID + col];
            a0 += y0[kk]*w; a1 += y1[kk]*w;
        }
        int rowA = r0 + rA, rowB = r0 + rB;
        float o0 = xs[rA][col] + a0;
        float o1 = xs[rB][col] + a1;
        if (logs[rowA] == 0) o0 = 0.f;
        if (logs[rowB] == 0) o1 = 0.f;
        sx[rA][col] = o0;
        sx[rB][col] = o1;
    }
    __syncthreads();

    // ---- LN + QKV phase (layer l+1) ----
    #pragma unroll
    for (int p = 0; p < 2; ++p) {
        int rr = g + p*4;
        int row = r0 + rr;
        float x = sx[rr][col];
        red[g][col] = x;
        __syncthreads();
        for (int off = 64; off; off >>= 1) { if (col < off) red[g][col] += red[g][col+off]; __syncthreads(); }
        float mu = red[g][0] * (1.f/HID);
        __syncthreads();
        float c = x - mu;
        red[g][col] = c*c; __syncthreads();
        for (int off = 64; off; off >>= 1) { if (col < off) red[g][col] += red[g][col+off]; __syncthreads(); }
        float ln = c * rsqrtf(red[g][0]*(1.f/HID) + LNEPS) * lns[col] + lnb[col];
        qn[rr][col] = ln;
        Qn[(size_t)row*HID + col] = ln;
        __syncthreads();
    }

    float aq0 = Qb[col], aq1 = aq0;
    float ak0 = Kb[col], ak1 = ak0;
    float av0 = Vb[col], av1 = av0;
    const float* q0 = qn[rA]; const float* q1 = qn[rB];
    const float* x0 = sx[rA]; const float* x1 = sx[rB];
    #pragma unroll 4
    for (int kk = 0; kk < HID; ++kk) {
        float wq = Qw[kk*HID + col];
        float wk = Kw[kk*HID + col];
        float wv = Vw[kk*HID + col];
        aq0 += q0[kk]*wq; aq1 += q1[kk]*wq;
        ak0 += x0[kk]*wk; ak1 += x1[kk]*wk;
        av0 += x0[kk]*wv; av1 += x1[kk]*wv;
    }
    int rowA = r0 + rA, rowB = r0 + rB;
    int lA = rowA % LL, lB = rowB % LL;
    qbuf[(size_t)rowA*HID + col] = aq0;
    qbuf[(size_t)rowB*HID + col] = aq1;
    kbuf[(size_t)rowA*HID + col] = ak0 + posK[lA*HID + col];
    kbuf[(size_t)rowB*HID + col] = ak1 + posK[lB*HID + col];
    vbuf[(size_t)rowA*HID + col] = av0 + posV[lA*HID + col];
    vbuf[(size_t)rowB*HID + col] = av1 + posV[lB*HID + col];
}

// ---------------- K3: FFN(layer 1) + last-LN + pos/neg logits, 8 rows/block
__global__ __launch_bounds__(512) void k_ffn_logits(
    const float* __restrict__ seqs_in,          // attn(1) output
    const float* __restrict__ flns, const float* __restrict__ flnb,
    const float* __restrict__ c1w, const float* __restrict__ c1b,
    const float* __restrict__ c2w, const float* __restrict__ c2b,
    const int* __restrict__ logs,
    const float* __restrict__ lls, const float* __restrict__ llb,
    const int* __restrict__ pos, const int* __restrict__ neg,
    const int* __restrict__ meta,
    const float* __restrict__ iW, const float* __restrict__ bW,
    const float* __restrict__ cW,
    float* __restrict__ out)
{
    __shared__ float xs[8][HID];
    __shared__ float h1[8][HID];
    __shared__ float red[4][HID];
    __shared__ float sx[8][HID];
    int tid = threadIdx.x;
    int g = tid >> 7, col = tid & 127;
    int r0 = blockIdx.x * 8;

    // ---- FFN phase ----
    #pragma unroll
    for (int p = 0; p < 2; ++p) {
        int rr = g + p*4;
        int row = r0 + rr;
        float x = seqs_in[(size_t)row*HID + col];
        red[g][col] = x;
        __syncthreads();
        for (int off = 64; off; off >>= 1) { if (col < off) red[g][col] += red[g][col+off]; __syncthreads(); }
        float mu = red[g][0] * (1.f/HID);
        __syncthreads();
        float c = x - mu;
        red[g][col] = c*c; __syncthreads();
        for (int off = 64; off; off >>= 1) { if (col < off) red[g][col] += red[g][col+off]; __syncthreads(); }
        xs[rr][col] = c * rsqrtf(red[g][0]*(1.f/HID) + LNEPS) * flns[col] + flnb[col];
        __syncthreads();
    }

    int rA = 2*g, rB = 2*g + 1;
    {
        float a0 = c1b[col], a1 = a0;
        const float* x0 = xs[rA]; const float* x1 = xs[rB];
        #pragma unroll 4
        for (int kk = 0; kk < HID; ++kk) {
            float w = c1w[kk*HID + col];
            a0 += x0[kk]*w; a1 += x1[kk]*w;
        }
        h1[rA][col] = fmaxf(a0, 0.f);
        h1[rB][col] = fmaxf(a1, 0.f);
    }
    __syncthreads();
    {
        float a0 = c2b[col], a1 = a0;
        const float* y0 = h1[rA]; const float* y1 = h1[rB];
        #pragma unroll 4
        for (int kk = 0; kk < HID; ++kk) {
            float w = c2w[kk*HID + col];
            a0 += y0[kk]*w; a1 += y1[kk]*w;
        }
        int rowA = r0 + rA, rowB = r0 + rB;
        float o0 = xs[rA][col] + a0;
        float o1 = xs[rB][col] + a1;
        if (logs[rowA] == 0) o0 = 0.f;
        if (logs[rowB] == 0) o1 = 0.f;
        sx[rA][col] = o0;
        sx[rB][col] = o1;
    }
    __syncthreads();

    // ---- last-LN + logits phase ----
    #pragma unroll
    for (int p = 0; p < 2; ++p) {
        int rr = g + p*4;
        int row = r0 + rr;
        float x = sx[rr][col];
        red[g][col] = x;
        __syncthreads();
        for (int off = 64; off; off >>= 1) { if (col < off) red[g][col] += red[g][col+off]; __syncthreads(); }
        float mu = red[g][0] * (1.f/HID);
        __syncthreads();
        float c = x - mu;
        red[g][col] = c*c; __syncthreads();
        for (int off = 64; off; off >>= 1) { if (col < off) red[g][col] += red[g][col+off]; __syncthreads(); }
        float f = c * rsqrtf(red[g][0]*(1.f/HID) + LNEPS) * lls[col] + llb[col];
        __syncthreads();

        int pid = pos[row];
        float e = embed_val(pid, col, meta, iW, bW, cW);
        red[g][col] = f * e; __syncthreads();
        for (int off = 64; off; off >>= 1) { if (col < off) red[g][col] += red[g][col+off]; __syncthreads(); }
        if (col == 0) out[row] = red[g][0];
        __syncthreads();

        int nid = neg[row];
        e = embed_val(nid, col, meta, iW, bW, cW);
        red[g][col] = f * e; __syncthreads();
        for (int off = 64; off; off >>= 1) { if (col < off) red[g][col] += red[g][col+off]; __syncthreads(); }
        if (col == 0) out[NROW + row] = red[g][0];
        __syncthreads();
    }
}

extern "C" void kernel_launch(void* const* d_in, const int* in_sizes, int n_in,
                              void* d_out, int out_size, void* d_ws, size_t ws_size,
                              hipStream_t stream)
{
    const int*  logs = (const int*)d_in[1];
    const int*  tmat = (const int*)d_in[2];
    const int*  pos  = (const int*)d_in[3];
    const int*  neg  = (const int*)d_in[4];
    const int*  meta = (const int*)d_in[5];
    const float* iW   = (const float*)d_in[6];
    const float* bW   = (const float*)d_in[7];
    const float* cW   = (const float*)d_in[8];
    const float* posK = (const float*)d_in[9];
    const float* posV = (const float*)d_in[10];
    const float* tK   = (const float*)d_in[11];
    const float* tV   = (const float*)d_in[12];
    const float* attn_s = (const float*)d_in[13];
    const float* attn_b = (const float*)d_in[14];
    const float* Qw = (const float*)d_in[15];
    const float* Qb = (const float*)d_in[16];
    const float* Kw = (const float*)d_in[17];
    const float* Kb = (const float*)d_in[18];
    const float* Vw = (const float*)d_in[19];
    const float* Vb = (const float*)d_in[20];
    const float* fwd_s = (const float*)d_in[21];
    const float* fwd_b = (const float*)d_in[22];
    const float* c1w = (const float*)d_in[23];
    const float* c1b = (const float*)d_in[24];
    const float* c2w = (const float*)d_in[25];
    const float* c2b = (const float*)d_in[26];
    const float* lls = (const float*)d_in[27];
    const float* llb = (const float*)d_in[28];

    const size_t RC = (size_t)NROW * HID;
    float* seqs = (float*)d_ws;        // attn output
    float* Qn   = seqs + RC;
    float* qbuf = Qn   + RC;
    float* kbuf = qbuf + RC;
    float* vbuf = kbuf + RC;

    const size_t W = (size_t)HID * HID;

    // layer 0: embed + LN + QKV
    k_emb_lnqkv<<<NROW/8, 512, 0, stream>>>(logs, meta, iW, bW, cW,
                                            attn_s, attn_b,
                                            Qw, Qb, Kw, Kb, Vw, Vb,
                                            posK, posV, Qn, qbuf, kbuf, vbuf);
    k_attn<<<NH*LL, 1024, 0, stream>>>(qbuf, (const float4*)kbuf,
                                       (const float4*)vbuf, (const float4*)Qn,
                                       (const float4*)tK, (const float4*)tV,
                                       tmat, logs, (float4*)seqs);
    // FFN(0) + LN(1) + QKV(1)
    k_ffn_lnqkv<<<NROW/8, 512, 0, stream>>>(seqs, fwd_s, fwd_b,
                                            c1w, c1b, c2w, c2b, logs,
                                            attn_s + HID, attn_b + HID,
                                            Qw + W, Qb + HID, Kw + W, Kb + HID,
                                            Vw + W, Vb + HID,
                                            posK, posV, Qn, qbuf, kbuf, vbuf);
    k_attn<<<NH*LL, 1024, 0, stream>>>(qbuf, (const float4*)kbuf,
                                       (const float4*)vbuf, (const float4*)Qn,
                                       (const float4*)tK, (const float4*)tV,
                                       tmat, logs, (float4*)seqs);
    // FFN(1) + last-LN + logits
    k_ffn_logits<<<NROW/8, 512, 0, stream>>>(seqs, fwd_s + HID, fwd_b + HID,
                                             c1w + W, c1b + HID, c2w + W, c2b + HID,
                                             logs, lls, llb, pos, neg, meta,
                                             iW, bW, cW, (float*)d_out);
}